// Round 1
// baseline (295.401 us; speedup 1.0000x reference)
//
#include <hip/hip_runtime.h>
#include <hip/hip_bf16.h>
#include <cstdint>
#include <cstddef>

#define N_TOK 8192
#define D_IN  1024
#define D_OUT 1024
#define N_EXP 8
#define KTOT  (N_EXP * D_IN)

#define BM    256
#define BN    128
#define BKH   32          // half-K step
#define NSTEP 256         // KTOT / BKH

typedef __attribute__((ext_vector_type(8))) short short8;
typedef __attribute__((ext_vector_type(8))) unsigned short ushort8;
typedef __attribute__((ext_vector_type(4))) float f32x4;

__device__ __forceinline__ unsigned short f2bf(float f) {
    union { float f; unsigned int u; } v; v.f = f;
    return (unsigned short)((v.u + 0x7FFFu + ((v.u >> 16) & 1u)) >> 16);
}

__device__ __forceinline__ void load_lds16(const void* g, void* l) {
    __builtin_amdgcn_global_load_lds(
        (const __attribute__((address_space(1))) void*)g,
        (__attribute__((address_space(3))) void*)l,
        16, 0, 0);
}

// ---------------------------------------------------------------------------
// Fused prep, 4096 blocks (UNCHANGED this round):
//   [0,2048)    : W[e][i][o] fp32 -> Wt[o][e*1024+i] bf16 (64x64 transpose)
//   [2048,4096) : gate softmax + x->bf16, one wave per token (4 tok/block)
// ---------------------------------------------------------------------------
__global__ __launch_bounds__(256) void prep_kernel(
    const float* __restrict__ x, const float* __restrict__ gW,
    const float* __restrict__ gbias, const float* __restrict__ W,
    unsigned short* __restrict__ xb, unsigned short* __restrict__ Wt,
    float* __restrict__ g_t) {
    const int b = blockIdx.x;
    const int t = threadIdx.x;

    if (b < 2048) {
        __shared__ float tile[64][65];
        const int e  = b >> 8;
        const int i0 = ((b >> 4) & 15) * 64;
        const int o0 = (b & 15) * 64;

        const int rr = t >> 4;
        const int rc = (t & 15) * 4;
#pragma unroll
        for (int j = 0; j < 4; ++j) {
            const float4 v = *(const float4*)(
                W + ((size_t)e * D_IN + (i0 + rr + 16 * j)) * D_OUT + o0 + rc);
            tile[rr + 16 * j][rc + 0] = v.x;
            tile[rr + 16 * j][rc + 1] = v.y;
            tile[rr + 16 * j][rc + 2] = v.z;
            tile[rr + 16 * j][rc + 3] = v.w;
        }
        __syncthreads();
        const int ow = t >> 2;
        const int c  = (t & 3) * 16;
        ushort8 v0, v1;
#pragma unroll
        for (int j = 0; j < 8; ++j) v0[j] = f2bf(tile[c + j][ow]);
#pragma unroll
        for (int j = 0; j < 8; ++j) v1[j] = f2bf(tile[c + 8 + j][ow]);
        unsigned short* dst = Wt + (size_t)(o0 + ow) * KTOT + e * D_IN + i0 + c;
        *(ushort8*)dst = v0;
        *(ushort8*)(dst + 8) = v1;
    } else {
        const int lane = t & 63;
        const int n    = (b - 2048) * 4 + (t >> 6);

        float acc[8];
#pragma unroll
        for (int e = 0; e < 8; ++e) acc[e] = 0.f;
#pragma unroll
        for (int jj = 0; jj < 4; ++jj) {
            const int i = 256 * jj + 4 * lane;
            const float4 xv = *(const float4*)(x + (size_t)n * D_IN + i);
            ushort4 u;
            u.x = f2bf(xv.x); u.y = f2bf(xv.y);
            u.z = f2bf(xv.z); u.w = f2bf(xv.w);
            *(ushort4*)(xb + (size_t)n * D_IN + i) = u;
            const float xs[4] = {xv.x, xv.y, xv.z, xv.w};
#pragma unroll
            for (int j = 0; j < 4; ++j) {
                const float* wr = gW + (size_t)(i + j) * N_EXP;
                const float4 w0 = *(const float4*)wr;
                const float4 w1 = *(const float4*)(wr + 4);
                acc[0] += xs[j] * w0.x; acc[1] += xs[j] * w0.y;
                acc[2] += xs[j] * w0.z; acc[3] += xs[j] * w0.w;
                acc[4] += xs[j] * w1.x; acc[5] += xs[j] * w1.y;
                acc[6] += xs[j] * w1.z; acc[7] += xs[j] * w1.w;
            }
        }
#pragma unroll
        for (int off = 32; off > 0; off >>= 1) {
#pragma unroll
            for (int e = 0; e < 8; ++e) acc[e] += __shfl_down(acc[e], off);
        }
        if (lane == 0) {
            float lg[8], mx = -1e30f;
#pragma unroll
            for (int e = 0; e < 8; ++e) {
                lg[e] = acc[e] + gbias[e];
                mx = fmaxf(mx, lg[e]);
            }
            float s = 0.f;
#pragma unroll
            for (int e = 0; e < 8; ++e) { lg[e] = expf(lg[e] - mx); s += lg[e]; }
            const float inv = 1.f / s;
#pragma unroll
            for (int e = 0; e < 8; ++e)
                g_t[(size_t)e * N_TOK + n] = lg[e] * inv;
        }
    }
}

// ---------------------------------------------------------------------------
// GEMM v8: BM=256 x BN=128 tile, 512 threads (8 waves, 4Mx2N, wave=64x64),
// half-K(32) pipeline with 4 LDS buffers (depth-3 prefetch), counted
// s_waitcnt vmcnt(6) across barriers (never drained in main loop), setprio
// around the 16-MFMA cluster, inherited zero-conflict XOR swizzle, and the
// telescoping gate rescale at expert boundaries (identical numerics to v6).
// Grid (8,32): flat%8 == blockIdx.x -> each XCD owns one N-column; its 2 MB
// B-panel stays L2-resident.
// ---------------------------------------------------------------------------
__global__ __launch_bounds__(512, 2) void moe_gemm8_kernel(
    const unsigned short* __restrict__ xb,   // [N_TOK][D_IN] bf16
    const unsigned short* __restrict__ Wt,   // [D_OUT][KTOT] bf16
    const float* __restrict__ bias,          // [N_EXP][D_OUT]
    const float* __restrict__ g_t,           // [N_EXP][N_TOK]
    float* __restrict__ out) {               // [N_TOK][D_OUT]
    __shared__ __align__(16) unsigned short A4[4][BM * BKH];  // 64 KB
    __shared__ __align__(16) unsigned short B4[4][BN * BKH];  // 32 KB
    __shared__ __align__(16) float g_s[N_EXP][BM];            // 8 KB
    __shared__ __align__(16) float r_s[N_EXP][BM];            // 8 KB
    __shared__ __align__(16) float b_s[N_EXP][BN];            // 4 KB

    const int t    = threadIdx.x;
    const int lane = t & 63;
    const int ln15 = lane & 15;
    const int quad = lane >> 4;
    const int wave = t >> 6;             // 0..7
    const int wm0  = (wave >> 1) * 64;   // 0,64,128,192
    const int wn0  = (wave & 1) * 64;    // 0,64

    const int bn0 = blockIdx.x * BN;     // 8 N-blocks
    const int bm0 = blockIdx.y * BM;     // 32 M-blocks

    for (int j = t; j < N_EXP * BM; j += 512)
        g_s[j >> 8][j & 255] = g_t[(size_t)(j >> 8) * N_TOK + bm0 + (j & 255)];
    for (int j = t; j < N_EXP * BN; j += 512)
        b_s[j >> 7][j & 127] = bias[(size_t)(j >> 7) * D_OUT + bn0 + (j & 127)];
    __syncthreads();
    if (t < BM) {
        float d[N_EXP];
#pragma unroll
        for (int e = 0; e < N_EXP; ++e) d[e] = fmaxf(g_s[e][t], 1e-30f);
#pragma unroll
        for (int e = 1; e < N_EXP; ++e) r_s[e][t] = d[e - 1] / d[e];
        r_s[0][t] = d[N_EXP - 1];
    }
    __syncthreads();   // r_s ready; nothing outstanding before staging begins

    f32x4 acc[4][4];
#pragma unroll
    for (int mi = 0; mi < 4; ++mi)
#pragma unroll
        for (int ni = 0; ni < 4; ++ni)
            acc[mi][ni] = (f32x4){0.f, 0.f, 0.f, 0.f};

    // Staging: thread t fills LDS slot (row t>>2 in [0,128), chunk t&3);
    // swizzled global source so slot chunk c' holds global chunk c'^((row>>1)&3).
    const int srow = t >> 2;
    const int csw  = ((t & 3) ^ ((t >> 3) & 3)) * 8;
    const unsigned short* gA = xb + (size_t)(bm0 + srow) * D_IN + csw;
    const unsigned short* gB = Wt + (size_t)(bn0 + srow) * (size_t)KTOT + csw;
    const int wrow = wave * 16 * BKH;   // wave-uniform LDS base (rows 16w..)

    // Fragment reads: chunk slot = quad ^ ((ln15>>1)&3)  (verified 0-conflict)
    const int ksw  = (quad ^ ((ln15 >> 1) & 3)) * 8;
    const int aoff = (wm0 + ln15) * BKH + ksw;
    const int boff = (wn0 + ln15) * BKH + ksw;

    // prologue: stage half-steps 0,1,2 (9 loads/wave); keep 6 in flight
#pragma unroll
    for (int s = 0; s < 3; ++s) {
        load_lds16(gA + s * BKH,              &A4[s][wrow]);
        load_lds16(gA + 128 * D_IN + s * BKH, &A4[s][128 * BKH + wrow]);
        load_lds16(gB + (size_t)s * BKH,      &B4[s][wrow]);
    }
    asm volatile("s_waitcnt vmcnt(6)" ::: "memory");
    __builtin_amdgcn_s_barrier();
    __builtin_amdgcn_sched_barrier(0);

#define HALF_STEP(h_, DO_STAGE)                                               \
  {                                                                           \
    const int slot_ = (h_) & 3;                                               \
    const unsigned short* Ab_ = &A4[slot_][0];                                \
    const unsigned short* Bb_ = &B4[slot_][0];                                \
    const int hs_ = (h_) + 3;                                                 \
    if ((h_) && !((h_) & 31)) {  /* telescoping rescale at expert entry */    \
      const int e_ = (h_) >> 5;                                               \
      _Pragma("unroll") for (int mi = 0; mi < 4; ++mi) {                      \
        const f32x4 rv = *(const f32x4*)&r_s[e_][wm0 + mi * 16 + quad * 4];   \
        _Pragma("unroll") for (int ni = 0; ni < 4; ++ni)                      \
          _Pragma("unroll") for (int r = 0; r < 4; ++r)                       \
            acc[mi][ni][r] *= rv[r];                                          \
      }                                                                       \
    }                                                                         \
    short8 af_[4], bv_[4];                                                    \
    _Pragma("unroll") for (int mi = 0; mi < 4; ++mi)                          \
      af_[mi] = *(const short8*)(Ab_ + aoff + mi * 16 * BKH);                 \
    _Pragma("unroll") for (int ni = 0; ni < 4; ++ni)                          \
      bv_[ni] = *(const short8*)(Bb_ + boff + ni * 16 * BKH);                 \
    if (DO_STAGE) {                                                           \
      load_lds16(gA + ((hs_) & 31) * BKH,              &A4[(hs_) & 3][wrow]); \
      load_lds16(gA + 128 * D_IN + ((hs_) & 31) * BKH,                        \
                 &A4[(hs_) & 3][128 * BKH + wrow]);                           \
      load_lds16(gB + (size_t)(hs_) * BKH,             &B4[(hs_) & 3][wrow]); \
    }                                                                         \
    __builtin_amdgcn_s_barrier();                                             \
    asm volatile("s_waitcnt lgkmcnt(0)" ::: "memory");                        \
    __builtin_amdgcn_sched_barrier(0);                                        \
    __builtin_amdgcn_s_setprio(1);                                            \
    _Pragma("unroll") for (int mi = 0; mi < 4; ++mi)                          \
      _Pragma("unroll") for (int ni = 0; ni < 4; ++ni)                        \
        acc[mi][ni] = __builtin_amdgcn_mfma_f32_16x16x32_bf16(                \
            af_[mi], bv_[ni], acc[mi][ni], 0, 0, 0);                          \
    __builtin_amdgcn_s_setprio(0);                                            \
  }

#define END_WAIT(N_)                                                          \
  asm volatile("s_waitcnt vmcnt(" #N_ ")" ::: "memory");                      \
  __builtin_amdgcn_s_barrier();                                               \
  __builtin_amdgcn_sched_barrier(0);

    for (int h = 0; h < NSTEP - 3; ++h) {   // h = 0..252, stages h+3
        HALF_STEP(h, 1);
        END_WAIT(6);
    }
    HALF_STEP(253, 0);
    END_WAIT(3);
    HALF_STEP(254, 0);
    END_WAIT(0);
    HALF_STEP(255, 0);

#undef HALF_STEP
#undef END_WAIT

    // final telescope scale by d[7], then add sum_e g_e * b[e][col]
#pragma unroll
    for (int mi = 0; mi < 4; ++mi) {
        const f32x4 fin = *(const f32x4*)&r_s[0][wm0 + mi * 16 + quad * 4];
#pragma unroll
        for (int ni = 0; ni < 4; ++ni)
#pragma unroll
            for (int r = 0; r < 4; ++r) acc[mi][ni][r] *= fin[r];
    }
#pragma unroll
    for (int e = 0; e < N_EXP; ++e) {
        f32x4 gv[4];
        float bb[4];
#pragma unroll
        for (int mi = 0; mi < 4; ++mi)
            gv[mi] = *(const f32x4*)&g_s[e][wm0 + mi * 16 + quad * 4];
#pragma unroll
        for (int ni = 0; ni < 4; ++ni) bb[ni] = b_s[e][wn0 + ni * 16 + ln15];
#pragma unroll
        for (int mi = 0; mi < 4; ++mi)
#pragma unroll
            for (int ni = 0; ni < 4; ++ni)
#pragma unroll
                for (int r = 0; r < 4; ++r)
                    acc[mi][ni][r] += gv[mi][r] * bb[ni];
    }

#pragma unroll
    for (int mi = 0; mi < 4; ++mi) {
#pragma unroll
        for (int ni = 0; ni < 4; ++ni) {
            const int col  = bn0 + wn0 + ni * 16 + ln15;
            const int row0 = bm0 + wm0 + mi * 16 + quad * 4;
#pragma unroll
            for (int r = 0; r < 4; ++r)
                out[(size_t)(row0 + r) * D_OUT + col] = acc[mi][ni][r];
        }
    }
}

// ---------------------------------------------------------------------------
extern "C" void kernel_launch(void* const* d_in, const int* in_sizes, int n_in,
                              void* d_out, int out_size, void* d_ws, size_t ws_size,
                              hipStream_t stream) {
    const float* x  = (const float*)d_in[0];
    const float* W  = (const float*)d_in[1];
    const float* b  = (const float*)d_in[2];
    const float* gW = (const float*)d_in[3];
    const float* gb = (const float*)d_in[4];
    float* out = (float*)d_out;

    unsigned short* xb  = (unsigned short*)d_ws;                 // 16 MB
    unsigned short* Wt  = xb + (size_t)N_TOK * D_IN;             // 16 MB
    float*          g_t = (float*)(Wt + (size_t)D_OUT * KTOT);   // 256 KB

    prep_kernel<<<4096, 256, 0, stream>>>(x, gW, gb, W, xb, Wt, g_t);
    moe_gemm8_kernel<<<dim3(D_OUT / BN, N_TOK / BM), 512, 0, stream>>>(
        xb, Wt, b, g_t, out);
}

// Round 2
// 283.804 us; speedup vs baseline: 1.0409x; 1.0409x over previous
//
#include <hip/hip_runtime.h>
#include <hip/hip_bf16.h>
#include <cstdint>
#include <cstddef>

#define N_TOK 8192
#define D_IN  1024
#define D_OUT 1024
#define N_EXP 8
#define KTOT  (N_EXP * D_IN)

#define BM    256
#define BN    128
#define BKH   32          // half-K step
#define NSTEP 256         // KTOT / BKH

typedef __attribute__((ext_vector_type(8))) short short8;
typedef __attribute__((ext_vector_type(8))) unsigned short ushort8;
typedef __attribute__((ext_vector_type(4))) float f32x4;

__device__ __forceinline__ unsigned short f2bf(float f) {
    union { float f; unsigned int u; } v; v.f = f;
    return (unsigned short)((v.u + 0x7FFFu + ((v.u >> 16) & 1u)) >> 16);
}

__device__ __forceinline__ void load_lds16(const void* g, void* l) {
    __builtin_amdgcn_global_load_lds(
        (const __attribute__((address_space(1))) void*)g,
        (__attribute__((address_space(3))) void*)l,
        16, 0, 0);
}

// ---------------------------------------------------------------------------
// Fused prep, 4096 blocks (UNCHANGED):
//   [0,2048)    : W[e][i][o] fp32 -> Wt[o][e*1024+i] bf16 (64x64 transpose)
//   [2048,4096) : gate softmax + x->bf16, one wave per token (4 tok/block)
// ---------------------------------------------------------------------------
__global__ __launch_bounds__(256) void prep_kernel(
    const float* __restrict__ x, const float* __restrict__ gW,
    const float* __restrict__ gbias, const float* __restrict__ W,
    unsigned short* __restrict__ xb, unsigned short* __restrict__ Wt,
    float* __restrict__ g_t) {
    const int b = blockIdx.x;
    const int t = threadIdx.x;

    if (b < 2048) {
        __shared__ float tile[64][65];
        const int e  = b >> 8;
        const int i0 = ((b >> 4) & 15) * 64;
        const int o0 = (b & 15) * 64;

        const int rr = t >> 4;
        const int rc = (t & 15) * 4;
#pragma unroll
        for (int j = 0; j < 4; ++j) {
            const float4 v = *(const float4*)(
                W + ((size_t)e * D_IN + (i0 + rr + 16 * j)) * D_OUT + o0 + rc);
            tile[rr + 16 * j][rc + 0] = v.x;
            tile[rr + 16 * j][rc + 1] = v.y;
            tile[rr + 16 * j][rc + 2] = v.z;
            tile[rr + 16 * j][rc + 3] = v.w;
        }
        __syncthreads();
        const int ow = t >> 2;
        const int c  = (t & 3) * 16;
        ushort8 v0, v1;
#pragma unroll
        for (int j = 0; j < 8; ++j) v0[j] = f2bf(tile[c + j][ow]);
#pragma unroll
        for (int j = 0; j < 8; ++j) v1[j] = f2bf(tile[c + 8 + j][ow]);
        unsigned short* dst = Wt + (size_t)(o0 + ow) * KTOT + e * D_IN + i0 + c;
        *(ushort8*)dst = v0;
        *(ushort8*)(dst + 8) = v1;
    } else {
        const int lane = t & 63;
        const int n    = (b - 2048) * 4 + (t >> 6);

        float acc[8];
#pragma unroll
        for (int e = 0; e < 8; ++e) acc[e] = 0.f;
#pragma unroll
        for (int jj = 0; jj < 4; ++jj) {
            const int i = 256 * jj + 4 * lane;
            const float4 xv = *(const float4*)(x + (size_t)n * D_IN + i);
            ushort4 u;
            u.x = f2bf(xv.x); u.y = f2bf(xv.y);
            u.z = f2bf(xv.z); u.w = f2bf(xv.w);
            *(ushort4*)(xb + (size_t)n * D_IN + i) = u;
            const float xs[4] = {xv.x, xv.y, xv.z, xv.w};
#pragma unroll
            for (int j = 0; j < 4; ++j) {
                const float* wr = gW + (size_t)(i + j) * N_EXP;
                const float4 w0 = *(const float4*)wr;
                const float4 w1 = *(const float4*)(wr + 4);
                acc[0] += xs[j] * w0.x; acc[1] += xs[j] * w0.y;
                acc[2] += xs[j] * w0.z; acc[3] += xs[j] * w0.w;
                acc[4] += xs[j] * w1.x; acc[5] += xs[j] * w1.y;
                acc[6] += xs[j] * w1.z; acc[7] += xs[j] * w1.w;
            }
        }
#pragma unroll
        for (int off = 32; off > 0; off >>= 1) {
#pragma unroll
            for (int e = 0; e < 8; ++e) acc[e] += __shfl_down(acc[e], off);
        }
        if (lane == 0) {
            float lg[8], mx = -1e30f;
#pragma unroll
            for (int e = 0; e < 8; ++e) {
                lg[e] = acc[e] + gbias[e];
                mx = fmaxf(mx, lg[e]);
            }
            float s = 0.f;
#pragma unroll
            for (int e = 0; e < 8; ++e) { lg[e] = expf(lg[e] - mx); s += lg[e]; }
            const float inv = 1.f / s;
#pragma unroll
            for (int e = 0; e < 8; ++e)
                g_t[(size_t)e * N_TOK + n] = lg[e] * inv;
        }
    }
}

// ---------------------------------------------------------------------------
// GEMM v9: v8's deep pipeline (BM=256 x BN=128, 512 thr / 8 waves, 4 LDS
// slots, depth-3 prefetch, counted vmcnt(6), setprio, zero-conflict XOR
// swizzle, telescoping rescale) + two fixes:
//   1. XCD super-tile: XCD i (flat&7) owns a 4M x 8N rectangle -> per-XCD
//      per-expert-pass working set = A 2MB + B 2MB = 4MB = L2. (v8 gave one
//      N-column per XCD: A 16MB -> L2 thrash, FETCH 533MB, fetch-bound.)
//   2. One barrier per half-step (the pre-MFMA barrier was redundant: the
//      previous step's vmcnt(6)+barrier already orders staging vs reads).
// ---------------------------------------------------------------------------
__global__ __launch_bounds__(512, 1) void moe_gemm9_kernel(
    const unsigned short* __restrict__ xb,   // [N_TOK][D_IN] bf16
    const unsigned short* __restrict__ Wt,   // [D_OUT][KTOT] bf16
    const float* __restrict__ bias,          // [N_EXP][D_OUT]
    const float* __restrict__ g_t,           // [N_EXP][N_TOK]
    float* __restrict__ out) {               // [N_TOK][D_OUT]
    __shared__ __align__(16) unsigned short A4[4][BM * BKH];  // 64 KB
    __shared__ __align__(16) unsigned short B4[4][BN * BKH];  // 32 KB
    __shared__ __align__(16) float g_s[N_EXP][BM];            // 8 KB
    __shared__ __align__(16) float r_s[N_EXP][BM];            // 8 KB
    __shared__ __align__(16) float b_s[N_EXP][BN];            // 4 KB

    const int t    = threadIdx.x;
    const int lane = t & 63;
    const int ln15 = lane & 15;
    const int quad = lane >> 4;
    const int wave = t >> 6;             // 0..7
    const int wm0  = (wave >> 1) * 64;   // 0,64,128,192
    const int wn0  = (wave & 1) * 64;    // 0,64

    // XCD super-tile: flat%8 = XCD (round-robin dispatch). XCD owns
    // M-rows [4*xcd, 4*xcd+4) x all 8 N-cols.
    const int flat = blockIdx.x + 8 * blockIdx.y;   // grid (8, 32)
    const int bn0  = ((flat >> 3) & 7) * BN;
    const int bm0  = ((flat & 7) * 4 + (flat >> 6)) * BM;

    for (int j = t; j < N_EXP * BM; j += 512)
        g_s[j >> 8][j & 255] = g_t[(size_t)(j >> 8) * N_TOK + bm0 + (j & 255)];
    for (int j = t; j < N_EXP * BN; j += 512)
        b_s[j >> 7][j & 127] = bias[(size_t)(j >> 7) * D_OUT + bn0 + (j & 127)];
    __syncthreads();
    if (t < BM) {
        float d[N_EXP];
#pragma unroll
        for (int e = 0; e < N_EXP; ++e) d[e] = fmaxf(g_s[e][t], 1e-30f);
#pragma unroll
        for (int e = 1; e < N_EXP; ++e) r_s[e][t] = d[e - 1] / d[e];
        r_s[0][t] = d[N_EXP - 1];
    }
    __syncthreads();   // r_s ready; nothing outstanding before staging begins

    f32x4 acc[4][4];
#pragma unroll
    for (int mi = 0; mi < 4; ++mi)
#pragma unroll
        for (int ni = 0; ni < 4; ++ni)
            acc[mi][ni] = (f32x4){0.f, 0.f, 0.f, 0.f};

    // Staging: thread t fills LDS slot (row t>>2 in [0,128), chunk t&3);
    // swizzled global source so slot chunk c' holds global chunk c'^((row>>1)&3).
    const int srow = t >> 2;
    const int csw  = ((t & 3) ^ ((t >> 3) & 3)) * 8;
    const unsigned short* gA = xb + (size_t)(bm0 + srow) * D_IN + csw;
    const unsigned short* gB = Wt + (size_t)(bn0 + srow) * (size_t)KTOT + csw;
    const int wrow = wave * 16 * BKH;   // wave-uniform LDS base (rows 16w..)

    // Fragment reads: chunk slot = quad ^ ((ln15>>1)&3)  (verified 0-conflict)
    const int ksw  = (quad ^ ((ln15 >> 1) & 3)) * 8;
    const int aoff = (wm0 + ln15) * BKH + ksw;
    const int boff = (wn0 + ln15) * BKH + ksw;

    // prologue: stage half-steps 0,1,2 (9 loads/thread); drain slot 0 only
#pragma unroll
    for (int s = 0; s < 3; ++s) {
        load_lds16(gA + s * BKH,              &A4[s][wrow]);
        load_lds16(gA + 128 * D_IN + s * BKH, &A4[s][128 * BKH + wrow]);
        load_lds16(gB + (size_t)s * BKH,      &B4[s][wrow]);
    }
    asm volatile("s_waitcnt vmcnt(6)" ::: "memory");
    __builtin_amdgcn_s_barrier();
    __builtin_amdgcn_sched_barrier(0);

// One barrier per half-step: [stage h+3] [rescale?] [frag reads] lgkmcnt(0)
// [16 MFMA] vmcnt(6) barrier.  Safety: barrier(h-1) happens after every
// wave's lgkmcnt(0) of step h-1, so all reads of slot (h+3)&3 are complete
// before any wave stages into it at step h; vmcnt(6) before barrier(h)
// guarantees slot (h+1)&3 fully landed in every wave before step h+1 reads.
#define HALF_STEP(h_, DO_STAGE)                                               \
  {                                                                           \
    const int slot_ = (h_) & 3;                                               \
    const unsigned short* Ab_ = &A4[slot_][0];                                \
    const unsigned short* Bb_ = &B4[slot_][0];                                \
    const int hs_ = (h_) + 3;                                                 \
    if (DO_STAGE) {                                                           \
      load_lds16(gA + ((hs_) & 31) * BKH,              &A4[(hs_) & 3][wrow]); \
      load_lds16(gA + 128 * D_IN + ((hs_) & 31) * BKH,                        \
                 &A4[(hs_) & 3][128 * BKH + wrow]);                           \
      load_lds16(gB + (size_t)(hs_) * BKH,             &B4[(hs_) & 3][wrow]); \
    }                                                                         \
    if ((h_) && !((h_) & 31)) {  /* telescoping rescale at expert entry */    \
      const int e_ = (h_) >> 5;                                               \
      _Pragma("unroll") for (int mi = 0; mi < 4; ++mi) {                      \
        const f32x4 rv = *(const f32x4*)&r_s[e_][wm0 + mi * 16 + quad * 4];   \
        _Pragma("unroll") for (int ni = 0; ni < 4; ++ni)                      \
          _Pragma("unroll") for (int r = 0; r < 4; ++r)                       \
            acc[mi][ni][r] *= rv[r];                                          \
      }                                                                       \
    }                                                                         \
    short8 af_[4], bv_[4];                                                    \
    _Pragma("unroll") for (int mi = 0; mi < 4; ++mi)                          \
      af_[mi] = *(const short8*)(Ab_ + aoff + mi * 16 * BKH);                 \
    _Pragma("unroll") for (int ni = 0; ni < 4; ++ni)                          \
      bv_[ni] = *(const short8*)(Bb_ + boff + ni * 16 * BKH);                 \
    asm volatile("s_waitcnt lgkmcnt(0)" ::: "memory");                        \
    __builtin_amdgcn_sched_barrier(0);                                        \
    __builtin_amdgcn_s_setprio(1);                                            \
    _Pragma("unroll") for (int mi = 0; mi < 4; ++mi)                          \
      _Pragma("unroll") for (int ni = 0; ni < 4; ++ni)                        \
        acc[mi][ni] = __builtin_amdgcn_mfma_f32_16x16x32_bf16(                \
            af_[mi], bv_[ni], acc[mi][ni], 0, 0, 0);                          \
    __builtin_amdgcn_s_setprio(0);                                            \
  }

#define END_WAIT(N_)                                                          \
  asm volatile("s_waitcnt vmcnt(" #N_ ")" ::: "memory");                      \
  __builtin_amdgcn_s_barrier();                                               \
  __builtin_amdgcn_sched_barrier(0);

#pragma unroll 4
    for (int h = 0; h < NSTEP - 4; ++h) {   // h = 0..251 (252 = 4*63)
        HALF_STEP(h, 1);
        END_WAIT(6);
    }
    HALF_STEP(252, 1);                      // stages 255 (last)
    END_WAIT(6);
    HALF_STEP(253, 0);
    END_WAIT(3);
    HALF_STEP(254, 0);
    END_WAIT(0);
    HALF_STEP(255, 0);

#undef HALF_STEP
#undef END_WAIT

    // final telescope scale by d[7], then add sum_e g_e * b[e][col]
#pragma unroll
    for (int mi = 0; mi < 4; ++mi) {
        const f32x4 fin = *(const f32x4*)&r_s[0][wm0 + mi * 16 + quad * 4];
#pragma unroll
        for (int ni = 0; ni < 4; ++ni)
#pragma unroll
            for (int r = 0; r < 4; ++r) acc[mi][ni][r] *= fin[r];
    }
#pragma unroll
    for (int e = 0; e < N_EXP; ++e) {
        f32x4 gv[4];
        float bb[4];
#pragma unroll
        for (int mi = 0; mi < 4; ++mi)
            gv[mi] = *(const f32x4*)&g_s[e][wm0 + mi * 16 + quad * 4];
#pragma unroll
        for (int ni = 0; ni < 4; ++ni) bb[ni] = b_s[e][wn0 + ni * 16 + ln15];
#pragma unroll
        for (int mi = 0; mi < 4; ++mi)
#pragma unroll
            for (int ni = 0; ni < 4; ++ni)
#pragma unroll
                for (int r = 0; r < 4; ++r)
                    acc[mi][ni][r] += gv[mi][r] * bb[ni];
    }

#pragma unroll
    for (int mi = 0; mi < 4; ++mi) {
#pragma unroll
        for (int ni = 0; ni < 4; ++ni) {
            const int col  = bn0 + wn0 + ni * 16 + ln15;
            const int row0 = bm0 + wm0 + mi * 16 + quad * 4;
#pragma unroll
            for (int r = 0; r < 4; ++r)
                out[(size_t)(row0 + r) * D_OUT + col] = acc[mi][ni][r];
        }
    }
}

// ---------------------------------------------------------------------------
extern "C" void kernel_launch(void* const* d_in, const int* in_sizes, int n_in,
                              void* d_out, int out_size, void* d_ws, size_t ws_size,
                              hipStream_t stream) {
    const float* x  = (const float*)d_in[0];
    const float* W  = (const float*)d_in[1];
    const float* b  = (const float*)d_in[2];
    const float* gW = (const float*)d_in[3];
    const float* gb = (const float*)d_in[4];
    float* out = (float*)d_out;

    unsigned short* xb  = (unsigned short*)d_ws;                 // 16 MB
    unsigned short* Wt  = xb + (size_t)N_TOK * D_IN;             // 16 MB
    float*          g_t = (float*)(Wt + (size_t)D_OUT * KTOT);   // 256 KB

    prep_kernel<<<4096, 256, 0, stream>>>(x, gW, gb, W, xb, Wt, g_t);
    moe_gemm9_kernel<<<dim3(D_OUT / BN, N_TOK / BM), 512, 0, stream>>>(
        xb, Wt, b, g_t, out);
}